// Round 6
// baseline (1344.275 us; speedup 1.0000x reference)
//
// R9: R8 (XCD-clustered, verified fast path: FETCH 648->24MB) + 3 latency cuts.
// R8 post-mortem: comm localized to XCD L2 but dur only -17% -> step (5640cy)
// still ~2.5x the handoff+compute floor. This round removes three serial
// contributors, no sync-structure changes:
//  (1) x[t] staging load was an HBM-cold miss (~900cy, x streams 21MB once)
//      INSIDE the staging phase -> prefetch x[t+1] into VGPRs during the
//      MFMA/gates phase (issued after staging barrier, drained by the
//      end-of-step barrier ~1200cy later): HBM latency fully overlapped.
//  (2) gg==0 layer1 wg computed the whole head (32 batches) -> constant
//      straggler under max-of-16 step semantics. Distribute: every layer1 wg
//      emits y for 2 batches (h2[t-1] for all 32 batches is in its LDS).
//  (3) staging vectorized: ring/LDS layout pairs exactly for even `up` ->
//      dwordx2 gather + ds_write_b64, half the issue count (FAST path only;
//      slow path byte-identical to R8's proven code).
#include <hip/hip_runtime.h>
#include <cstdint>

#define B_TOT 256
#define T_LEN 512
#define NX    40
#define NH    250
#define HP    256          // hidden padded (dummy units produce h=0, W cols 0)
#define XP    64           // x padded
#define K0    (XP + HP)    // 320  (layer0: [x | h1_prev])
#define K1    (HP + HP)    // 512  (layer1: [h1_t | h2_prev])
#define MB    32           // batches per wg
#define NU    16           // hidden units per wg
#define NR    64           // gate rows per wg (NU*4, r = lu*4 + gate; i,f,g,o)
#define RING  8            // broadcast ring depth
#define LDSK  520          // LDS K-stride in ushorts (16B aligned; 260 dwords)
#define SLOTS 16           // ints per slot (64B stride, own cache line)
#define NFLAG (2 * 8 * 16 * SLOTS)   // 4096 ints of flag slots (16KB)
#define RSTEP (B_TOT * HP / 2)       // 32768 dwords per ring slot
// h ring (dwords): slot*RSTEP + gb*4096 + gg*256 + eb*8 + up
//   where dword (gg,up) of batch eb = bf16 units (gg*16+2up, gg*16+2up+1)
#define XCD_AT(w) ((w) * SLOTS + 8)
#define BAR_IDX 9
// s_getreg imm: id | (offset<<6) | ((size-1)<<11); XCC_ID id=20, 32 bits.
#define GETREG_XCC 63508

typedef __attribute__((ext_vector_type(8))) short short8;
typedef __attribute__((ext_vector_type(4))) float float4v;

__device__ __forceinline__ unsigned short f2bf(float f) {
  unsigned u = __float_as_uint(f);
  u += 0x7FFFu + ((u >> 16) & 1u);          // RNE
  return (unsigned short)(u >> 16);
}
__device__ __forceinline__ float bf2f(unsigned short h) {
  return __uint_as_float(((unsigned)h) << 16);
}
__device__ __forceinline__ float sigm(float x) { return 1.0f / (1.0f + __expf(-x)); }
__device__ __forceinline__ float tanh_f(float x) {
  float e = __expf(-2.0f * fabsf(x));
  float t = (1.0f - e) / (1.0f + e);
  return copysignf(t, x);
}
__device__ __forceinline__ unsigned ld_lic(const unsigned* p) {   // sc1 dword load
  return __hip_atomic_load(p, __ATOMIC_RELAXED, __HIP_MEMORY_SCOPE_AGENT);
}
// CU-local L1 invalidate: subsequent plain loads are (at least) L2-fresh.
__device__ __forceinline__ void inv_l1() {
  asm volatile("buffer_inv\n\ts_waitcnt vmcnt(0)" ::: "memory");
  __builtin_amdgcn_sched_barrier(0);
}
template <bool FAST>
__device__ __forceinline__ void sth(unsigned* p, unsigned v) {
  if (FAST) *p = v;        // plain store: write-through L1 -> local L2
  else __hip_atomic_store(p, v, __ATOMIC_RELAXED, __HIP_MEMORY_SCOPE_AGENT);
}

// ---------------------------------------------------------------------------
// Per-layer persistent loop. LAYER=0: x(40->64 pad)+h1_prev, K=320.
// LAYER=1: h1_t + h2_prev, K=512; every layer1 wg emits y for 2 batches.
// Slot value = number of completed steps by that wg.
// ---------------------------------------------------------------------------
template <int KSTEPS, int LAYER, bool FAST>
__device__ __forceinline__ void run_layer(
    int tid, int gg, int b0, int u0,
    const float* __restrict__ x, float* __restrict__ out, float blinv,
    unsigned short* __restrict__ h1bc, unsigned short* __restrict__ h2bc,
    int* __restrict__ c0s, int* __restrict__ c1s, int* __restrict__ mys,
    unsigned short (*WL)[LDSK], unsigned short (*inA)[LDSK],
    float (*gbuf)[NR + 4], float* biasS, float* wlinS) {
  const int lane = tid & 63, wv = tid >> 6;
  const int quad = lane >> 4, l15 = lane & 15;
  const int Mt = wv & 1, Np = wv >> 1;   // wave -> (M-tile, N-tile-pair)
  const int gb = b0 >> 5;
  const int irow = tid >> 3, icol = tid & 7;   // slow-path scatter coords
  // FAST vectorized gather coords: pairs (g = 8*hi + k, up = q2, q2+1)
  const int eb = tid >> 3, p8 = tid & 7, hi = p8 >> 2, q2 = 2 * (p8 & 3);

  // Preload B fragments (constant across time): B[k][n]=WL[n-row][k];
  // lane layout n = lane&15, k = quad*8 + j.
  short8 bfrag[2][KSTEPS];
#pragma unroll
  for (int ks = 0; ks < KSTEPS; ++ks) {
#pragma unroll
    for (int i = 0; i < 2; ++i)
      bfrag[i][ks] = *(const short8*)&WL[Np * 32 + i * 16 + l15][ks * 32 + quad * 8];
  }

  // x prefetch registers (layer0, threads 0..127): holds x[t] during step t-1
  float xr[10];
  if (LAYER == 0 && tid < 128) {
    int b = tid >> 2, c = tid & 3;
    const float* xp0 = x + ((size_t)(b0 + b) * T_LEN + 0) * NX + c * 10;
#pragma unroll
    for (int j = 0; j < 10; ++j) xr[j] = xp0[j];
  }

  // cell state for (batch b0+tid>>3, units u0+2*(tid&7), +1): fp32 registers
  float cA = 0.f, cB = 0.f;

#pragma unroll 1
  for (int t = 0; t < T_LEN; ++t) {
    // ---- wait for producers: wave0 lanes 0..31 poll one slot each (sc1
    //      relaxed loads in BOTH paths: always fresh -> no hang).
    if (wv == 0 && lane < 32) {
      const int* sl = ((lane < 16) ? c0s : c1s) + (lane & 15) * SLOTS;
      int thr;
      if (LAYER == 0) thr = (lane < 16) ? t : (t - RING + 1);
      else            thr = (lane < 16) ? (t + 1) : t;
      while (__hip_atomic_load(sl, __ATOMIC_RELAXED, __HIP_MEMORY_SCOPE_AGENT) < thr) {
        __builtin_amdgcn_s_sleep(1);
      }
    }
    __syncthreads();
    // FAST data freshness: drop CU L1 so the plain gather loads read the XCD
    // L2 (where the producers' write-through stores live).
    if (FAST && (LAYER == 1 || t > 0)) inv_l1();

    // ---- stage inputs into LDS (bf16) ----
    if (LAYER == 0) {
      if (FAST) {
        uint2 v[8];
        if (t > 0) {
          const unsigned* s1 = (const unsigned*)h1bc +
              ((size_t)((t - 1) & (RING - 1)) * RSTEP + (size_t)gb * 4096);
#pragma unroll
          for (int k = 0; k < 8; ++k)
            v[k] = *(const uint2*)(s1 + (8 * hi + k) * 256 + eb * 8 + q2);
        }
        if (tid < 128) {   // x[b,t,0:40] from prefetch regs (40..63 stay zero)
          int b = tid >> 2, c = tid & 3;
#pragma unroll
          for (int j = 0; j < 10; ++j) inA[b][c * 10 + j] = f2bf(xr[j]);
        }
        if (t > 0) {
          unsigned* row = (unsigned*)&inA[eb][0];
#pragma unroll
          for (int k = 0; k < 8; ++k)
            *(uint2*)&row[32 + (8 * hi + k) * 8 + q2] = v[k];
        }
      } else {
        if (t > 0) {
          const unsigned* s1 = (const unsigned*)h1bc +
              ((size_t)((t - 1) & (RING - 1)) * RSTEP + (size_t)gb * 4096);
          unsigned v[16];
#pragma unroll
          for (int k = 0; k < 16; ++k) v[k] = ld_lic(s1 + tid + k * 256);
#pragma unroll
          for (int k = 0; k < 16; ++k)
            ((unsigned*)&inA[irow][0])[32 + k * 8 + icol] = v[k];
        }
        if (tid < 128) {
          int b = tid >> 2, c = tid & 3;
#pragma unroll
          for (int j = 0; j < 10; ++j) inA[b][c * 10 + j] = f2bf(xr[j]);
        }
      }
    } else {
      const unsigned* s1 = (const unsigned*)h1bc +
          ((size_t)(t & (RING - 1)) * RSTEP + (size_t)gb * 4096);
      const unsigned* s2 = (const unsigned*)h2bc +
          ((size_t)((t - 1) & (RING - 1)) * RSTEP + (size_t)gb * 4096);
      if (FAST) {
        uint2 va[8], vb[8];
#pragma unroll
        for (int k = 0; k < 8; ++k)
          va[k] = *(const uint2*)(s1 + (8 * hi + k) * 256 + eb * 8 + q2);
        if (t > 0) {
#pragma unroll
          for (int k = 0; k < 8; ++k)
            vb[k] = *(const uint2*)(s2 + (8 * hi + k) * 256 + eb * 8 + q2);
        }
        unsigned* row = (unsigned*)&inA[eb][0];
#pragma unroll
        for (int k = 0; k < 8; ++k) {
          *(uint2*)&row[(8 * hi + k) * 8 + q2] = va[k];
          if (t > 0) *(uint2*)&row[128 + (8 * hi + k) * 8 + q2] = vb[k];
        }
      } else {
        unsigned va[16], vb[16];
#pragma unroll
        for (int k = 0; k < 16; ++k) va[k] = ld_lic(s1 + tid + k * 256);
        if (t > 0) {
#pragma unroll
          for (int k = 0; k < 16; ++k) vb[k] = ld_lic(s2 + tid + k * 256);
        }
#pragma unroll
        for (int k = 0; k < 16; ++k) {
          unsigned* row = (unsigned*)&inA[irow][0];
          row[k * 8 + icol] = va[k];
          if (t > 0) row[128 + k * 8 + icol] = vb[k];
        }
      }
    }
    __syncthreads();

    // ---- prefetch x[t+1] into regs: issued now, drained by the end-of-step
    //      barrier ~1200cy later -> HBM latency hidden under compute.
    if (LAYER == 0 && tid < 128 && t + 1 < T_LEN) {
      int b = tid >> 2, c = tid & 3;
      const float* xp = x + ((size_t)(b0 + b) * T_LEN + (size_t)(t + 1)) * NX + c * 10;
#pragma unroll
      for (int j = 0; j < 10; ++j) xr[j] = xp[j];
    }

    // ---- gate GEMM: D[b][r] = sum_k inA[b][k] * WL[r][k] ----
    float4v acc0 = {0.f, 0.f, 0.f, 0.f};
    float4v acc1 = {0.f, 0.f, 0.f, 0.f};
#pragma unroll
    for (int ks = 0; ks < KSTEPS; ++ks) {
      short8 a = *(const short8*)&inA[Mt * 16 + l15][ks * 32 + quad * 8];
      acc0 = __builtin_amdgcn_mfma_f32_16x16x32_bf16(a, bfrag[0][ks], acc0, 0, 0, 0);
      acc1 = __builtin_amdgcn_mfma_f32_16x16x32_bf16(a, bfrag[1][ks], acc1, 0, 0, 0);
    }
    // dump C (row b = Mt*16+quad*4+reg, col r = Ntile*16 + l15)
#pragma unroll
    for (int reg = 0; reg < 4; ++reg) {
      gbuf[Mt * 16 + quad * 4 + reg][Np * 32 + l15] = acc0[reg];
      gbuf[Mt * 16 + quad * 4 + reg][Np * 32 + 16 + l15] = acc1[reg];
    }
    __syncthreads();

    // ---- gates + state update; write h (bf16). Store = base+tid: 256
    //      consecutive dwords per wg. FAST: plain store -> local XCD L2;
    //      slow: sc1 write-through to LIC.
    {
      int ebg = tid >> 3, up = tid & 7;
      float4v ga = *(const float4v*)&gbuf[ebg][up * 8];
      float4v gv = *(const float4v*)&gbuf[ebg][up * 8 + 4];
      float iA = sigm(ga[0] + biasS[up * 8 + 0]);
      float fA = sigm(ga[1] + biasS[up * 8 + 1]);
      float gA = tanh_f(ga[2] + biasS[up * 8 + 2]);
      float oA = sigm(ga[3] + biasS[up * 8 + 3]);
      cA = fA * cA + iA * gA;
      float hA = oA * tanh_f(cA);
      float iB = sigm(gv[0] + biasS[up * 8 + 4]);
      float fB = sigm(gv[1] + biasS[up * 8 + 5]);
      float gB = tanh_f(gv[2] + biasS[up * 8 + 6]);
      float oB = sigm(gv[3] + biasS[up * 8 + 7]);
      cB = fB * cB + iB * gB;
      float hB = oB * tanh_f(cB);
      unsigned hv = (unsigned)f2bf(hA) | ((unsigned)f2bf(hB) << 16);
      unsigned* dst = (unsigned*)(LAYER ? h2bc : h1bc);
      size_t di = (size_t)(t & (RING - 1)) * RSTEP + (size_t)gb * 4096 +
                  (size_t)gg * 256 + tid;
      sth<FAST>(dst + di, hv);
    }

    // barrier drains every wave's vmcnt(0) -> all h stores (and the x
    // prefetch) are complete; then a relaxed flag store suffices.
    __syncthreads();
    if (tid == 0)
      sth<FAST>((unsigned*)mys, (unsigned)(t + 1));

    // ---- head: y[b, t-1] — distributed: each layer1 wg emits 2 batches
    //      (h2[t-1] for all 32 batches is staged in this wg's inA).
    if (LAYER == 1 && t > 0 && tid < 16) {
      int eb2 = 2 * gg + (tid >> 3), uc = tid & 7;
      float sum = 0.f;
#pragma unroll
      for (int j = 0; j < 4; ++j) {
        short8 hvv = *(const short8*)&inA[eb2][HP + uc * 32 + j * 8];
#pragma unroll
        for (int e = 0; e < 8; ++e)
          sum += bf2f((unsigned short)hvv[e]) * wlinS[uc * 32 + j * 8 + e];
      }
      sum += __shfl_xor(sum, 1);
      sum += __shfl_xor(sum, 2);
      sum += __shfl_xor(sum, 4);
      if ((tid & 7) == 0)
        out[(size_t)(b0 + eb2) * T_LEN + (t - 1)] = sigm(sum + blinv);
    }
  }

  // ---- epilogue: y[:, 511] — distributed: every layer1 wg, 2 batches ----
  if (LAYER == 1) {
    if (wv == 0 && lane < 16) {
      const int* sl = c1s + lane * SLOTS;
      while (__hip_atomic_load(sl, __ATOMIC_RELAXED, __HIP_MEMORY_SCOPE_AGENT) < T_LEN) {
        __builtin_amdgcn_s_sleep(1);
      }
    }
    __syncthreads();
    if (FAST) inv_l1();
    if (tid < 16) {
      int eb2 = 2 * gg + (tid >> 3), uc = tid & 7;
      // units uc*32..+31 of batch b0+eb2 live in gg-blocks 2*uc, 2*uc+1:
      // dword = (2*uc+g)*256 + eb2*8 + j  ->  units (2*uc+g)*16 + 2*j, +1
      const unsigned* base = (const unsigned*)h2bc +
          ((size_t)(511 & (RING - 1)) * RSTEP + (size_t)gb * 4096);
      float sum = 0.f;
#pragma unroll
      for (int g = 0; g < 2; ++g) {
        const unsigned* src = base + (size_t)(2 * uc + g) * 256 + eb2 * 8;
#pragma unroll
        for (int j = 0; j < 8; ++j) {
          unsigned dw = FAST ? src[j] : ld_lic(src + j);
          sum += bf2f((unsigned short)(dw & 0xFFFFu)) * wlinS[uc * 32 + g * 16 + 2 * j];
          sum += bf2f((unsigned short)(dw >> 16)) * wlinS[uc * 32 + g * 16 + 2 * j + 1];
        }
      }
      sum += __shfl_xor(sum, 1);
      sum += __shfl_xor(sum, 2);
      sum += __shfl_xor(sum, 4);
      if ((tid & 7) == 0)
        out[(size_t)(b0 + eb2) * T_LEN + 511] = sigm(sum + blinv);
    }
  }
}

// ---------------------------------------------------------------------------
extern "C" __global__ void __launch_bounds__(256, 1) lstm_persist(
    const float* __restrict__ x,
    const float* __restrict__ Wih0, const float* __restrict__ Whh0,
    const float* __restrict__ bih0, const float* __restrict__ bhh0,
    const float* __restrict__ Wih1, const float* __restrict__ Whh1,
    const float* __restrict__ bih1, const float* __restrict__ bhh1,
    const float* __restrict__ Wlin, const float* __restrict__ blin,
    float* __restrict__ out,
    unsigned short* __restrict__ h1bc, unsigned short* __restrict__ h2bc,
    int* __restrict__ cnt) {
  __shared__ unsigned short WL[NR][LDSK];    // 66560 B  bf16 [r][k], r = lu*4+gate
  __shared__ unsigned short inA[MB][LDSK];   // 33280 B  bf16 [b][k]
  __shared__ float gbuf[MB][NR + 4];         //  8704 B  fp32 gate preacts
  __shared__ float biasS[NR];
  __shared__ float wlinS[HP];

  const int tid = threadIdx.x;
  const int wg = blockIdx.x;

  // ---- XCD discovery + dynamic clustering (one-time, off steady state) ----
  const unsigned xcc = ((unsigned)__builtin_amdgcn_s_getreg(GETREG_XCC)) & 15u;
  if (tid == 0) {
    __hip_atomic_store(cnt + XCD_AT(wg), (int)xcc, __ATOMIC_RELAXED,
                       __HIP_MEMORY_SCOPE_AGENT);
    __hip_atomic_fetch_add(cnt + BAR_IDX, 1, __ATOMIC_ACQ_REL,
                           __HIP_MEMORY_SCOPE_AGENT);
    while (__hip_atomic_load(cnt + BAR_IDX, __ATOMIC_ACQUIRE,
                             __HIP_MEMORY_SCOPE_AGENT) < 256)
      __builtin_amdgcn_s_sleep(8);
  }
  __syncthreads();
  int* sx = (int*)&gbuf[0][0];   // reuse gbuf as 256-int scratch
  sx[tid] = __hip_atomic_load(cnt + XCD_AT(tid), __ATOMIC_RELAXED,
                              __HIP_MEMORY_SCOPE_AGENT);
  __syncthreads();
  const int myv = sx[wg];
  int rank = 0;
  unsigned long long hist = 0;   // 8 byte-counters (no scratch array, rule #20)
  bool ok = true;
  for (int j = 0; j < 256; ++j) {
    int v = sx[j];
    if ((unsigned)v > 7u) { ok = false; v = 0; }
    hist += 1ull << (v * 8);
    if (v == myv && j < wg) rank++;
  }
  ok = ok && (hist == 0x2020202020202020ull);   // exactly 32 wgs per XCD
  __syncthreads();   // sx (gbuf) free for steady-state reuse

  // Roles: fast -> cluster = this XCD (gb = xcd id, rank -> layer/unit-group);
  //        slow -> static mapping + sc1 comm ops (always correct).
  int layer, gb, gg;
  if (ok) { gb = myv;       layer = rank >> 4;    gg = rank & 15; }
  else    { layer = wg >> 7; gb = (wg >> 4) & 7;  gg = wg & 15;   }
  const int b0 = gb * MB, u0 = gg * NU;

  // ---- one-time LDS fills ----
  {
    const float* Wih = layer ? Wih1 : Wih0;
    const float* Whh = layer ? Whh1 : Whh0;
    const float* bi = layer ? bih1 : bih0;
    const float* bh = layer ? bhh1 : bhh0;
    const int K = layer ? K1 : K0;
    const int xw = layer ? NH : NX;     // real width of input-part
    const int xofs = layer ? HP : XP;   // where h-part starts
    int r = tid >> 2, c = tid & 3;
    int lu = r >> 2, g = r & 3, ug = u0 + lu;
    int row = g * NH + ug;
    int kq = K >> 2;
    for (int k = c * kq; k < (c + 1) * kq; ++k) {
      float v = 0.f;
      if (ug < NH) {
        if (k < xw) v = Wih[(size_t)row * xw + k];
        else if (k >= xofs && k < xofs + NH) v = Whh[(size_t)row * NH + (k - xofs)];
      }
      WL[r][k] = f2bf(v);
    }
    if (tid < NR) {
      int lu2 = tid >> 2, g2 = tid & 3, ug2 = u0 + lu2;
      biasS[tid] = (ug2 < NH) ? (bi[g2 * NH + ug2] + bh[g2 * NH + ug2]) : 0.f;
    }
    if (tid < HP) wlinS[tid] = (tid < NH) ? Wlin[tid] : 0.f;
    for (int i = tid; i < MB * LDSK; i += 256) ((unsigned short*)inA)[i] = 0;
  }
  __syncthreads();

  float blinv = blin[0];
  int* c0s = cnt + gb * 16 * SLOTS;              // layer0 slots, batch-group gb
  int* c1s = cnt + (8 + gb) * 16 * SLOTS;        // layer1 slots
  int* mys = (layer ? c1s : c0s) + gg * SLOTS;   // own slot

  if (ok) {
    if (layer == 0)
      run_layer<K0 / 32, 0, true>(tid, gg, b0, u0, x, out, blinv, h1bc, h2bc,
                                  c0s, c1s, mys, WL, inA, gbuf, biasS, wlinS);
    else
      run_layer<K1 / 32, 1, true>(tid, gg, b0, u0, x, out, blinv, h1bc, h2bc,
                                  c0s, c1s, mys, WL, inA, gbuf, biasS, wlinS);
  } else {
    if (layer == 0)
      run_layer<K0 / 32, 0, false>(tid, gg, b0, u0, x, out, blinv, h1bc, h2bc,
                                   c0s, c1s, mys, WL, inA, gbuf, biasS, wlinS);
    else
      run_layer<K1 / 32, 1, false>(tid, gg, b0, u0, x, out, blinv, h1bc, h2bc,
                                   c0s, c1s, mys, WL, inA, gbuf, biasS, wlinS);
  }
}

extern "C" __global__ void prep_zero(int* cnt) {
  int i = blockIdx.x * 256 + threadIdx.x;
  if (i < NFLAG)   // flag slots incl. embedded barrier/xcd-id padding ints
    __hip_atomic_store(cnt + i, 0, __ATOMIC_RELAXED, __HIP_MEMORY_SCOPE_AGENT);
}

// ---------------------------------------------------------------------------
extern "C" void kernel_launch(void* const* d_in, const int* in_sizes, int n_in,
                              void* d_out, int out_size, void* d_ws, size_t ws_size,
                              hipStream_t stream) {
  const float* x    = (const float*)d_in[0];
  const float* Wih0 = (const float*)d_in[1];
  const float* Whh0 = (const float*)d_in[2];
  const float* bih0 = (const float*)d_in[3];
  const float* bhh0 = (const float*)d_in[4];
  const float* Wih1 = (const float*)d_in[5];
  const float* Whh1 = (const float*)d_in[6];
  const float* bih1 = (const float*)d_in[7];
  const float* bhh1 = (const float*)d_in[8];
  const float* Wlin = (const float*)d_in[9];
  const float* blin = (const float*)d_in[10];
  float* out = (float*)d_out;

  // workspace carve (same footprint as R3/R7/R8): h rings 2x2MB | counters 16KB
  unsigned short* h1bc = (unsigned short*)d_ws;
  unsigned short* h2bc = h1bc + (size_t)RING * B_TOT * HP;
  int* cnt = (int*)((char*)d_ws + 2u * (size_t)RING * B_TOT * HP * sizeof(unsigned short));

  hipLaunchKernelGGL(prep_zero, dim3(16), dim3(256), 0, stream, cnt);

  void* args[] = {&x, &Wih0, &Whh0, &bih0, &bhh0, &Wih1, &Whh1, &bih1, &bhh1,
                  &Wlin, &blin, &out, &h1bc, &h2bc, &cnt};
  hipLaunchCooperativeKernel((void*)lstm_persist, dim3(256), dim3(256), args, 0u, stream);
}

// Round 8
// 1216.534 us; speedup vs baseline: 1.1050x; 1.1050x over previous
//
// R11: run-proven pieces only. == R9 (ran, 1285us) with its one identified
// regression reverted + one innocuous addition:
//  - staging: R8's scalar dword gather/scatter (R9's dwordx2/ds_write_b64
//    doubled SQ_LDS_BANK_CONFLICT 5.9e7->1.1e8 and cost +80us -> reverted).
//  - inv_l1: R9's exact scope/placement (ALL threads, AFTER the post-poll
//    __syncthreads) — run-proven in R8+R9. (R10's wave0-only/pre-barrier
//    variant was the only novel construct in the round that died.)
//  - kept from R9: x[t+1] register prefetch, distributed head (2 batches
//    per layer1 wg), XCD fast path + verified fallback, flag protocol.
//  - added: gate-bias hoist to 8 VGPRs (was 8 LDS reads/thread/step).
// Session evidence: FAST path engaged (FETCH 648->24MB), time is the
// poll->stage->signal latency chain; every novel sync construct cost a
// no-data round -> this round reassembles strictly from executed code.
#include <hip/hip_runtime.h>
#include <cstdint>

#define B_TOT 256
#define T_LEN 512
#define NX    40
#define NH    250
#define HP    256          // hidden padded (dummy units produce h=0, W cols 0)
#define XP    64           // x padded
#define K0    (XP + HP)    // 320  (layer0: [x | h1_prev])
#define K1    (HP + HP)    // 512  (layer1: [h1_t | h2_prev])
#define MB    32           // batches per wg
#define NU    16           // hidden units per wg
#define NR    64           // gate rows per wg (NU*4, r = lu*4 + gate; i,f,g,o)
#define RING  8            // broadcast ring depth
#define LDSK  520          // LDS K-stride in ushorts (16B aligned; 260 dwords)
#define SLOTS 16           // ints per slot (64B stride, own cache line)
#define NFLAG (2 * 8 * 16 * SLOTS)   // 4096 ints of flag slots (16KB)
#define RSTEP (B_TOT * HP / 2)       // 32768 dwords per ring slot
// h ring (dwords): slot*RSTEP + gb*4096 + gg*256 + eb*8 + up
//   where dword (gg,up) of batch eb = bf16 units (gg*16+2up, gg*16+2up+1)
#define XCD_AT(w) ((w) * SLOTS + 8)
#define BAR_IDX 9
// s_getreg imm: id | (offset<<6) | ((size-1)<<11); XCC_ID id=20, 32 bits.
#define GETREG_XCC 63508

typedef __attribute__((ext_vector_type(8))) short short8;
typedef __attribute__((ext_vector_type(4))) float float4v;

__device__ __forceinline__ unsigned short f2bf(float f) {
  unsigned u = __float_as_uint(f);
  u += 0x7FFFu + ((u >> 16) & 1u);          // RNE
  return (unsigned short)(u >> 16);
}
__device__ __forceinline__ float bf2f(unsigned short h) {
  return __uint_as_float(((unsigned)h) << 16);
}
__device__ __forceinline__ float sigm(float x) { return 1.0f / (1.0f + __expf(-x)); }
__device__ __forceinline__ float tanh_f(float x) {
  float e = __expf(-2.0f * fabsf(x));
  float t = (1.0f - e) / (1.0f + e);
  return copysignf(t, x);
}
__device__ __forceinline__ unsigned ld_lic(const unsigned* p) {   // sc1 dword load
  return __hip_atomic_load(p, __ATOMIC_RELAXED, __HIP_MEMORY_SCOPE_AGENT);
}
// CU-local L1 invalidate: subsequent plain loads are (at least) L2-fresh.
__device__ __forceinline__ void inv_l1() {
  asm volatile("buffer_inv\n\ts_waitcnt vmcnt(0)" ::: "memory");
  __builtin_amdgcn_sched_barrier(0);
}
template <bool FAST>
__device__ __forceinline__ unsigned ldh(const unsigned* p) {
  if (FAST) return *p;     // plain load, L2-served (post-inv)
  return ld_lic(p);
}
template <bool FAST>
__device__ __forceinline__ void sth(unsigned* p, unsigned v) {
  if (FAST) *p = v;        // plain store: write-through L1 -> local L2
  else __hip_atomic_store(p, v, __ATOMIC_RELAXED, __HIP_MEMORY_SCOPE_AGENT);
}

// ---------------------------------------------------------------------------
// Per-layer persistent loop. LAYER=0: x(40->64 pad)+h1_prev, K=320.
// LAYER=1: h1_t + h2_prev, K=512; every layer1 wg emits y for 2 batches.
// Slot value = number of completed steps by that wg.
// ---------------------------------------------------------------------------
template <int KSTEPS, int LAYER, bool FAST>
__device__ __forceinline__ void run_layer(
    int tid, int gg, int b0, int u0,
    const float* __restrict__ x, float* __restrict__ out, float blinv,
    unsigned short* __restrict__ h1bc, unsigned short* __restrict__ h2bc,
    int* __restrict__ c0s, int* __restrict__ c1s, int* __restrict__ mys,
    unsigned short (*WL)[LDSK], unsigned short (*inA)[LDSK],
    float (*gbuf)[NR + 4], float* biasS, float* wlinS) {
  const int lane = tid & 63, wv = tid >> 6;
  const int quad = lane >> 4, l15 = lane & 15;
  const int Mt = wv & 1, Np = wv >> 1;   // wave -> (M-tile, N-tile-pair)
  const int gb = b0 >> 5;
  const int irow = tid >> 3, icol = tid & 7;   // gather->LDS scatter coords

  // Preload B fragments (constant across time): B[k][n]=WL[n-row][k];
  // lane layout n = lane&15, k = quad*8 + j.
  short8 bfrag[2][KSTEPS];
#pragma unroll
  for (int ks = 0; ks < KSTEPS; ++ks) {
#pragma unroll
    for (int i = 0; i < 2; ++i)
      bfrag[i][ks] = *(const short8*)&WL[Np * 32 + i * 16 + l15][ks * 32 + quad * 8];
  }

  // hoist gate biases (constant across time): 8 regs, was 8 LDS reads/step
  float bloc[8];
#pragma unroll
  for (int i = 0; i < 8; ++i) bloc[i] = biasS[(tid & 7) * 8 + i];

  // x prefetch registers (layer0, threads 0..127): holds x[t] during step t-1
  float xr[10];
  if (LAYER == 0 && tid < 128) {
    int b = tid >> 2, c = tid & 3;
    const float* xp0 = x + ((size_t)(b0 + b) * T_LEN + 0) * NX + c * 10;
#pragma unroll
    for (int j = 0; j < 10; ++j) xr[j] = xp0[j];
  }

  // cell state for (batch b0+tid>>3, units u0+2*(tid&7), +1): fp32 registers
  float cA = 0.f, cB = 0.f;

#pragma unroll 1
  for (int t = 0; t < T_LEN; ++t) {
    // ---- wait for producers: wave0 lanes 0..31 poll one slot each (sc1
    //      relaxed loads in BOTH paths: always fresh -> no hang).
    if (wv == 0 && lane < 32) {
      const int* sl = ((lane < 16) ? c0s : c1s) + (lane & 15) * SLOTS;
      int thr;
      if (LAYER == 0) thr = (lane < 16) ? t : (t - RING + 1);
      else            thr = (lane < 16) ? (t + 1) : t;
      while (__hip_atomic_load(sl, __ATOMIC_RELAXED, __HIP_MEMORY_SCOPE_AGENT) < thr) {
        __builtin_amdgcn_s_sleep(1);
      }
    }
    __syncthreads();
    // FAST data freshness: drop CU L1 so the plain gather loads read the XCD
    // L2 (where the producers' write-through stores live). [R8/R9-proven]
    if (FAST && (LAYER == 1 || t > 0)) inv_l1();

    // ---- stage inputs into LDS (bf16); coalesced scalar dword gather ----
    if (LAYER == 0) {
      if (t > 0) {
        const unsigned* s1 = (const unsigned*)h1bc +
            ((size_t)((t - 1) & (RING - 1)) * RSTEP + (size_t)gb * 4096);
        unsigned v[16];
#pragma unroll
        for (int k = 0; k < 16; ++k) v[k] = ldh<FAST>(s1 + tid + k * 256);
#pragma unroll
        for (int k = 0; k < 16; ++k)   // dword (gg=k, up=icol) of batch irow
          ((unsigned*)&inA[irow][0])[32 + k * 8 + icol] = v[k];   // +XP ushorts
      }
      if (tid < 128) {   // x[b,t,0:40] from prefetch regs (40..63 stay zero)
        int b = tid >> 2, c = tid & 3;
#pragma unroll
        for (int j = 0; j < 10; ++j) inA[b][c * 10 + j] = f2bf(xr[j]);
      }
    } else {
      const unsigned* s1 = (const unsigned*)h1bc +
          ((size_t)(t & (RING - 1)) * RSTEP + (size_t)gb * 4096);
      unsigned va[16], vb[16];
#pragma unroll
      for (int k = 0; k < 16; ++k) va[k] = ldh<FAST>(s1 + tid + k * 256);
      if (t > 0) {
        const unsigned* s2 = (const unsigned*)h2bc +
            ((size_t)((t - 1) & (RING - 1)) * RSTEP + (size_t)gb * 4096);
#pragma unroll
        for (int k = 0; k < 16; ++k) vb[k] = ldh<FAST>(s2 + tid + k * 256);
      }
#pragma unroll
      for (int k = 0; k < 16; ++k) {
        unsigned* row = (unsigned*)&inA[irow][0];
        row[k * 8 + icol] = va[k];                    // h1 at ushort 0
        if (t > 0) row[128 + k * 8 + icol] = vb[k];   // h2 at ushort HP
      }
    }
    __syncthreads();

    // ---- prefetch x[t+1] into regs: issued now, drained by the end-of-step
    //      barrier -> HBM latency hidden under the MFMA/gates phase.
    if (LAYER == 0 && tid < 128 && t + 1 < T_LEN) {
      int b = tid >> 2, c = tid & 3;
      const float* xp = x + ((size_t)(b0 + b) * T_LEN + (size_t)(t + 1)) * NX + c * 10;
#pragma unroll
      for (int j = 0; j < 10; ++j) xr[j] = xp[j];
    }

    // ---- gate GEMM: D[b][r] = sum_k inA[b][k] * WL[r][k] ----
    float4v acc0 = {0.f, 0.f, 0.f, 0.f};
    float4v acc1 = {0.f, 0.f, 0.f, 0.f};
#pragma unroll
    for (int ks = 0; ks < KSTEPS; ++ks) {
      short8 a = *(const short8*)&inA[Mt * 16 + l15][ks * 32 + quad * 8];
      acc0 = __builtin_amdgcn_mfma_f32_16x16x32_bf16(a, bfrag[0][ks], acc0, 0, 0, 0);
      acc1 = __builtin_amdgcn_mfma_f32_16x16x32_bf16(a, bfrag[1][ks], acc1, 0, 0, 0);
    }
    // dump C (row b = Mt*16+quad*4+reg, col r = Ntile*16 + l15)
#pragma unroll
    for (int reg = 0; reg < 4; ++reg) {
      gbuf[Mt * 16 + quad * 4 + reg][Np * 32 + l15] = acc0[reg];
      gbuf[Mt * 16 + quad * 4 + reg][Np * 32 + 16 + l15] = acc1[reg];
    }
    __syncthreads();

    // ---- gates + state update; write h (bf16). Store = base+tid: 256
    //      consecutive dwords per wg. FAST: plain store -> local XCD L2;
    //      slow: sc1 write-through to LIC.
    {
      int ebg = tid >> 3;
      float4v ga = *(const float4v*)&gbuf[ebg][(tid & 7) * 8];
      float4v gv = *(const float4v*)&gbuf[ebg][(tid & 7) * 8 + 4];
      float iA = sigm(ga[0] + bloc[0]);
      float fA = sigm(ga[1] + bloc[1]);
      float gA = tanh_f(ga[2] + bloc[2]);
      float oA = sigm(ga[3] + bloc[3]);
      cA = fA * cA + iA * gA;
      float hA = oA * tanh_f(cA);
      float iB = sigm(gv[0] + bloc[4]);
      float fB = sigm(gv[1] + bloc[5]);
      float gB = tanh_f(gv[2] + bloc[6]);
      float oB = sigm(gv[3] + bloc[7]);
      cB = fB * cB + iB * gB;
      float hB = oB * tanh_f(cB);
      unsigned hv = (unsigned)f2bf(hA) | ((unsigned)f2bf(hB) << 16);
      unsigned* dst = (unsigned*)(LAYER ? h2bc : h1bc);
      size_t di = (size_t)(t & (RING - 1)) * RSTEP + (size_t)gb * 4096 +
                  (size_t)gg * 256 + tid;
      sth<FAST>(dst + di, hv);
    }

    // barrier drains every wave's vmcnt(0) -> all h stores (and the x
    // prefetch) are complete; then a relaxed flag store suffices.
    __syncthreads();
    if (tid == 0)
      sth<FAST>((unsigned*)mys, (unsigned)(t + 1));

    // ---- head: y[b, t-1] — distributed: each layer1 wg emits 2 batches
    //      (h2[t-1] for all 32 batches is staged in this wg's inA).
    if (LAYER == 1 && t > 0 && tid < 16) {
      int eb2 = 2 * gg + (tid >> 3), uc = tid & 7;
      float sum = 0.f;
#pragma unroll
      for (int j = 0; j < 4; ++j) {
        short8 hvv = *(const short8*)&inA[eb2][HP + uc * 32 + j * 8];
#pragma unroll
        for (int e = 0; e < 8; ++e)
          sum += bf2f((unsigned short)hvv[e]) * wlinS[uc * 32 + j * 8 + e];
      }
      sum += __shfl_xor(sum, 1);
      sum += __shfl_xor(sum, 2);
      sum += __shfl_xor(sum, 4);
      if ((tid & 7) == 0)
        out[(size_t)(b0 + eb2) * T_LEN + (t - 1)] = sigm(sum + blinv);
    }
  }

  // ---- epilogue: y[:, 511] — distributed: every layer1 wg, 2 batches ----
  if (LAYER == 1) {
    if (wv == 0 && lane < 16) {
      const int* sl = c1s + lane * SLOTS;
      while (__hip_atomic_load(sl, __ATOMIC_RELAXED, __HIP_MEMORY_SCOPE_AGENT) < T_LEN) {
        __builtin_amdgcn_s_sleep(1);
      }
    }
    __syncthreads();
    if (FAST) inv_l1();
    if (tid < 16) {
      int eb2 = 2 * gg + (tid >> 3), uc = tid & 7;
      // units uc*32..+31 of batch b0+eb2 live in gg-blocks 2*uc, 2*uc+1:
      // dword = (2*uc+g)*256 + eb2*8 + j  ->  units (2*uc+g)*16 + 2*j, +1
      const unsigned* base = (const unsigned*)h2bc +
          ((size_t)(511 & (RING - 1)) * RSTEP + (size_t)gb * 4096);
      float sum = 0.f;
#pragma unroll
      for (int g = 0; g < 2; ++g) {
        const unsigned* src = base + (size_t)(2 * uc + g) * 256 + eb2 * 8;
#pragma unroll
        for (int j = 0; j < 8; ++j) {
          unsigned dw = ldh<FAST>(src + j);
          sum += bf2f((unsigned short)(dw & 0xFFFFu)) * wlinS[uc * 32 + g * 16 + 2 * j];
          sum += bf2f((unsigned short)(dw >> 16)) * wlinS[uc * 32 + g * 16 + 2 * j + 1];
        }
      }
      sum += __shfl_xor(sum, 1);
      sum += __shfl_xor(sum, 2);
      sum += __shfl_xor(sum, 4);
      if ((tid & 7) == 0)
        out[(size_t)(b0 + eb2) * T_LEN + 511] = sigm(sum + blinv);
    }
  }
}

// ---------------------------------------------------------------------------
extern "C" __global__ void __launch_bounds__(256, 1) lstm_persist(
    const float* __restrict__ x,
    const float* __restrict__ Wih0, const float* __restrict__ Whh0,
    const float* __restrict__ bih0, const float* __restrict__ bhh0,
    const float* __restrict__ Wih1, const float* __restrict__ Whh1,
    const float* __restrict__ bih1, const float* __restrict__ bhh1,
    const float* __restrict__ Wlin, const float* __restrict__ blin,
    float* __restrict__ out,
    unsigned short* __restrict__ h1bc, unsigned short* __restrict__ h2bc,
    int* __restrict__ cnt) {
  __shared__ unsigned short WL[NR][LDSK];    // 66560 B  bf16 [r][k], r = lu*4+gate
  __shared__ unsigned short inA[MB][LDSK];   // 33280 B  bf16 [b][k]
  __shared__ float gbuf[MB][NR + 4];         //  8704 B  fp32 gate preacts
  __shared__ float biasS[NR];
  __shared__ float wlinS[HP];

  const int tid = threadIdx.x;
  const int wg = blockIdx.x;

  // ---- XCD discovery + dynamic clustering (one-time, off steady state) ----
  const unsigned xcc = ((unsigned)__builtin_amdgcn_s_getreg(GETREG_XCC)) & 15u;
  if (tid == 0) {
    __hip_atomic_store(cnt + XCD_AT(wg), (int)xcc, __ATOMIC_RELAXED,
                       __HIP_MEMORY_SCOPE_AGENT);
    __hip_atomic_fetch_add(cnt + BAR_IDX, 1, __ATOMIC_ACQ_REL,
                           __HIP_MEMORY_SCOPE_AGENT);
    while (__hip_atomic_load(cnt + BAR_IDX, __ATOMIC_ACQUIRE,
                             __HIP_MEMORY_SCOPE_AGENT) < 256)
      __builtin_amdgcn_s_sleep(8);
  }
  __syncthreads();
  int* sx = (int*)&gbuf[0][0];   // reuse gbuf as 256-int scratch
  sx[tid] = __hip_atomic_load(cnt + XCD_AT(tid), __ATOMIC_RELAXED,
                              __HIP_MEMORY_SCOPE_AGENT);
  __syncthreads();
  const int myv = sx[wg];
  int rank = 0;
  unsigned long long hist = 0;   // 8 byte-counters (no scratch array, rule #20)
  bool ok = true;
  for (int j = 0; j < 256; ++j) {
    int v = sx[j];
    if ((unsigned)v > 7u) { ok = false; v = 0; }
    hist += 1ull << (v * 8);
    if (v == myv && j < wg) rank++;
  }
  ok = ok && (hist == 0x2020202020202020ull);   // exactly 32 wgs per XCD
  __syncthreads();   // sx (gbuf) free for steady-state reuse

  // Roles: fast -> cluster = this XCD (gb = xcd id, rank -> layer/unit-group);
  //        slow -> static mapping + sc1 comm ops (always correct).
  int layer, gb, gg;
  if (ok) { gb = myv;       layer = rank >> 4;    gg = rank & 15; }
  else    { layer = wg >> 7; gb = (wg >> 4) & 7;  gg = wg & 15;   }
  const int b0 = gb * MB, u0 = gg * NU;

  // ---- one-time LDS fills ----
  {
    const float* Wih = layer ? Wih1 : Wih0;
    const float* Whh = layer ? Whh1 : Whh0;
    const float* bi = layer ? bih1 : bih0;
    const float* bh = layer ? bhh1 : bhh0;
    const int K = layer ? K1 : K0;
    const int xw = layer ? NH : NX;     // real width of input-part
    const int xofs = layer ? HP : XP;   // where h-part starts
    int r = tid >> 2, c = tid & 3;
    int lu = r >> 2, g = r & 3, ug = u0 + lu;
    int row = g * NH + ug;
    int kq = K >> 2;
    for (int k = c * kq; k < (c + 1) * kq; ++k) {
      float v = 0.f;
      if (ug < NH) {
        if (k < xw) v = Wih[(size_t)row * xw + k];
        else if (k >= xofs && k < xofs + NH) v = Whh[(size_t)row * NH + (k - xofs)];
      }
      WL[r][k] = f2bf(v);
    }
    if (tid < NR) {
      int lu2 = tid >> 2, g2 = tid & 3, ug2 = u0 + lu2;
      biasS[tid] = (ug2 < NH) ? (bi[g2 * NH + ug2] + bh[g2 * NH + ug2]) : 0.f;
    }
    if (tid < HP) wlinS[tid] = (tid < NH) ? Wlin[tid] : 0.f;
    for (int i = tid; i < MB * LDSK; i += 256) ((unsigned short*)inA)[i] = 0;
  }
  __syncthreads();

  float blinv = blin[0];
  int* c0s = cnt + gb * 16 * SLOTS;              // layer0 slots, batch-group gb
  int* c1s = cnt + (8 + gb) * 16 * SLOTS;        // layer1 slots
  int* mys = (layer ? c1s : c0s) + gg * SLOTS;   // own slot

  if (ok) {
    if (layer == 0)
      run_layer<K0 / 32, 0, true>(tid, gg, b0, u0, x, out, blinv, h1bc, h2bc,
                                  c0s, c1s, mys, WL, inA, gbuf, biasS, wlinS);
    else
      run_layer<K1 / 32, 1, true>(tid, gg, b0, u0, x, out, blinv, h1bc, h2bc,
                                  c0s, c1s, mys, WL, inA, gbuf, biasS, wlinS);
  } else {
    if (layer == 0)
      run_layer<K0 / 32, 0, false>(tid, gg, b0, u0, x, out, blinv, h1bc, h2bc,
                                   c0s, c1s, mys, WL, inA, gbuf, biasS, wlinS);
    else
      run_layer<K1 / 32, 1, false>(tid, gg, b0, u0, x, out, blinv, h1bc, h2bc,
                                   c0s, c1s, mys, WL, inA, gbuf, biasS, wlinS);
  }
}

extern "C" __global__ void prep_zero(int* cnt) {
  int i = blockIdx.x * 256 + threadIdx.x;
  if (i < NFLAG)   // flag slots incl. embedded barrier/xcd-id padding ints
    __hip_atomic_store(cnt + i, 0, __ATOMIC_RELAXED, __HIP_MEMORY_SCOPE_AGENT);
}

// ---------------------------------------------------------------------------
extern "C" void kernel_launch(void* const* d_in, const int* in_sizes, int n_in,
                              void* d_out, int out_size, void* d_ws, size_t ws_size,
                              hipStream_t stream) {
  const float* x    = (const float*)d_in[0];
  const float* Wih0 = (const float*)d_in[1];
  const float* Whh0 = (const float*)d_in[2];
  const float* bih0 = (const float*)d_in[3];
  const float* bhh0 = (const float*)d_in[4];
  const float* Wih1 = (const float*)d_in[5];
  const float* Whh1 = (const float*)d_in[6];
  const float* bih1 = (const float*)d_in[7];
  const float* bhh1 = (const float*)d_in[8];
  const float* Wlin = (const float*)d_in[9];
  const float* blin = (const float*)d_in[10];
  float* out = (float*)d_out;

  // workspace carve (same footprint as R3/R7/R8): h rings 2x2MB | counters 16KB
  unsigned short* h1bc = (unsigned short*)d_ws;
  unsigned short* h2bc = h1bc + (size_t)RING * B_TOT * HP;
  int* cnt = (int*)((char*)d_ws + 2u * (size_t)RING * B_TOT * HP * sizeof(unsigned short));

  hipLaunchKernelGGL(prep_zero, dim3(16), dim3(256), 0, stream, cnt);

  void* args[] = {&x, &Wih0, &Whh0, &bih0, &bhh0, &Wih1, &Whh1, &bih1, &bhh1,
                  &Wlin, &blin, &out, &h1bc, &h2bc, &cnt};
  hipLaunchCooperativeKernel((void*)lstm_persist, dim3(256), dim3(256), args, 0u, stream);
}

// Round 9
// 1188.594 us; speedup vs baseline: 1.1310x; 1.0235x over previous
//
// R12: R11 (proven 1165us best) + MFMA operand swap -> in-register gates.
// R11 post-mortem: prediction matched (1204->1165, conflicts back to 6.0e7).
// Remaining period 5460cy has FOUR barriers; barrier #3 exists only for the
// gbuf LDS round-trip (MFMA D[batch][r] lane layout != gates' needs).
// R12: compute D[r][batch] = mfma(A=W, B=act) instead. Verified C/D layout
// (row=quad*4+reg, col=l15) -> lane holds ALL 4 gates of unit lu=rtile*4+quad
// for batch Mt*16+l15: gates fully lane-local. Index algebra: the W-fragment
// preload and act LDS read are BYTE-IDENTICAL to R11's (only mfma args swap).
// Deleted: gbuf dump, barrier #3, gbuf reads (8 LDS writes + sync + 2 b128
// reads per thread-step). h-pack: __shfl_xor(h,16) pairs adjacent quads;
// even-quad lanes store unit-pair dwords (up = Np*4+{0,2}+(quad>>1)).
// Staging / poll / flag / XCD fast-path: byte-identical to R11.
#include <hip/hip_runtime.h>
#include <cstdint>

#define B_TOT 256
#define T_LEN 512
#define NX    40
#define NH    250
#define HP    256          // hidden padded (dummy units produce h=0, W cols 0)
#define XP    64           // x padded
#define K0    (XP + HP)    // 320  (layer0: [x | h1_prev])
#define K1    (HP + HP)    // 512  (layer1: [h1_t | h2_prev])
#define MB    32           // batches per wg
#define NU    16           // hidden units per wg
#define NR    64           // gate rows per wg (NU*4, r = lu*4 + gate; i,f,g,o)
#define RING  8            // broadcast ring depth
#define LDSK  520          // LDS K-stride in ushorts (16B aligned; 260 dwords)
#define SLOTS 16           // ints per slot (64B stride, own cache line)
#define NFLAG (2 * 8 * 16 * SLOTS)   // 4096 ints of flag slots (16KB)
#define RSTEP (B_TOT * HP / 2)       // 32768 dwords per ring slot
// h ring (dwords): slot*RSTEP + gb*4096 + gg*256 + eb*8 + up
//   where dword (gg,up) of batch eb = bf16 units (gg*16+2up, gg*16+2up+1)
#define XCD_AT(w) ((w) * SLOTS + 8)
#define BAR_IDX 9
// s_getreg imm: id | (offset<<6) | ((size-1)<<11); XCC_ID id=20, 32 bits.
#define GETREG_XCC 63508

typedef __attribute__((ext_vector_type(8))) short short8;
typedef __attribute__((ext_vector_type(4))) float float4v;

__device__ __forceinline__ unsigned short f2bf(float f) {
  unsigned u = __float_as_uint(f);
  u += 0x7FFFu + ((u >> 16) & 1u);          // RNE
  return (unsigned short)(u >> 16);
}
__device__ __forceinline__ float bf2f(unsigned short h) {
  return __uint_as_float(((unsigned)h) << 16);
}
__device__ __forceinline__ float sigm(float x) { return 1.0f / (1.0f + __expf(-x)); }
__device__ __forceinline__ float tanh_f(float x) {
  float e = __expf(-2.0f * fabsf(x));
  float t = (1.0f - e) / (1.0f + e);
  return copysignf(t, x);
}
__device__ __forceinline__ unsigned ld_lic(const unsigned* p) {   // sc1 dword load
  return __hip_atomic_load(p, __ATOMIC_RELAXED, __HIP_MEMORY_SCOPE_AGENT);
}
// CU-local L1 invalidate: subsequent plain loads are (at least) L2-fresh.
__device__ __forceinline__ void inv_l1() {
  asm volatile("buffer_inv\n\ts_waitcnt vmcnt(0)" ::: "memory");
  __builtin_amdgcn_sched_barrier(0);
}
template <bool FAST>
__device__ __forceinline__ unsigned ldh(const unsigned* p) {
  if (FAST) return *p;     // plain load, L2-served (post-inv)
  return ld_lic(p);
}
template <bool FAST>
__device__ __forceinline__ void sth(unsigned* p, unsigned v) {
  if (FAST) *p = v;        // plain store: write-through L1 -> local L2
  else __hip_atomic_store(p, v, __ATOMIC_RELAXED, __HIP_MEMORY_SCOPE_AGENT);
}

// ---------------------------------------------------------------------------
// Per-layer persistent loop. LAYER=0: x(40->64 pad)+h1_prev, K=320.
// LAYER=1: h1_t + h2_prev, K=512; every layer1 wg emits y for 2 batches.
// Slot value = number of completed steps by that wg.
// ---------------------------------------------------------------------------
template <int KSTEPS, int LAYER, bool FAST>
__device__ __forceinline__ void run_layer(
    int tid, int gg, int b0, int u0,
    const float* __restrict__ x, float* __restrict__ out, float blinv,
    unsigned short* __restrict__ h1bc, unsigned short* __restrict__ h2bc,
    int* __restrict__ c0s, int* __restrict__ c1s, int* __restrict__ mys,
    unsigned short (*WL)[LDSK], unsigned short (*inA)[LDSK],
    float (*gbuf)[NR + 4], float* biasS, float* wlinS) {
  const int lane = tid & 63, wv = tid >> 6;
  const int quad = lane >> 4, l15 = lane & 15;
  const int Mt = wv & 1, Np = wv >> 1;   // wave -> (batch-tile, r-tile-pair)
  const int gb = b0 >> 5;
  const int irow = tid >> 3, icol = tid & 7;   // gather->LDS scatter coords

  // Preload W fragments (constant across time). As the MFMA *A* operand:
  // A[m][k] with m=l15 (tile row r), k=quad*8+j — indices byte-identical to
  // R11's B-operand preload; only the mfma argument position changes.
  short8 wfrag[2][KSTEPS];
#pragma unroll
  for (int ks = 0; ks < KSTEPS; ++ks) {
#pragma unroll
    for (int i = 0; i < 2; ++i)
      wfrag[i][ks] = *(const short8*)&WL[Np * 32 + i * 16 + l15][ks * 32 + quad * 8];
  }

  // hoist gate biases: lane handles gate rows r = (Np*2+j)*16 + quad*4 + reg
  float4v b4A = *(const float4v*)&biasS[Np * 32 + quad * 4];
  float4v b4B = *(const float4v*)&biasS[Np * 32 + 16 + quad * 4];

  // x prefetch registers (layer0, threads 0..127): holds x[t] during step t-1
  float xr[10];
  if (LAYER == 0 && tid < 128) {
    int b = tid >> 2, c = tid & 3;
    const float* xp0 = x + ((size_t)(b0 + b) * T_LEN + 0) * NX + c * 10;
#pragma unroll
    for (int j = 0; j < 10; ++j) xr[j] = xp0[j];
  }

  // cell state: lane owns (unit Np*8+quad, batch Mt*16+l15) -> cA
  //             and (unit Np*8+4+quad, same batch)          -> cB
  float cA = 0.f, cB = 0.f;

#pragma unroll 1
  for (int t = 0; t < T_LEN; ++t) {
    // ---- wait for producers: wave0 lanes 0..31 poll one slot each (sc1
    //      relaxed loads in BOTH paths: always fresh -> no hang).
    if (wv == 0 && lane < 32) {
      const int* sl = ((lane < 16) ? c0s : c1s) + (lane & 15) * SLOTS;
      int thr;
      if (LAYER == 0) thr = (lane < 16) ? t : (t - RING + 1);
      else            thr = (lane < 16) ? (t + 1) : t;
      while (__hip_atomic_load(sl, __ATOMIC_RELAXED, __HIP_MEMORY_SCOPE_AGENT) < thr) {
        __builtin_amdgcn_s_sleep(1);
      }
    }
    __syncthreads();
    // FAST data freshness: drop CU L1 so the plain gather loads read the XCD
    // L2 (where the producers' write-through stores live). [R8/R9/R11-proven]
    if (FAST && (LAYER == 1 || t > 0)) inv_l1();

    // ---- stage inputs into LDS (bf16); coalesced scalar dword gather ----
    if (LAYER == 0) {
      if (t > 0) {
        const unsigned* s1 = (const unsigned*)h1bc +
            ((size_t)((t - 1) & (RING - 1)) * RSTEP + (size_t)gb * 4096);
        unsigned v[16];
#pragma unroll
        for (int k = 0; k < 16; ++k) v[k] = ldh<FAST>(s1 + tid + k * 256);
#pragma unroll
        for (int k = 0; k < 16; ++k)   // dword (gg=k, up=icol) of batch irow
          ((unsigned*)&inA[irow][0])[32 + k * 8 + icol] = v[k];   // +XP ushorts
      }
      if (tid < 128) {   // x[b,t,0:40] from prefetch regs (40..63 stay zero)
        int b = tid >> 2, c = tid & 3;
#pragma unroll
        for (int j = 0; j < 10; ++j) inA[b][c * 10 + j] = f2bf(xr[j]);
      }
    } else {
      const unsigned* s1 = (const unsigned*)h1bc +
          ((size_t)(t & (RING - 1)) * RSTEP + (size_t)gb * 4096);
      unsigned va[16], vb[16];
#pragma unroll
      for (int k = 0; k < 16; ++k) va[k] = ldh<FAST>(s1 + tid + k * 256);
      if (t > 0) {
        const unsigned* s2 = (const unsigned*)h2bc +
            ((size_t)((t - 1) & (RING - 1)) * RSTEP + (size_t)gb * 4096);
#pragma unroll
        for (int k = 0; k < 16; ++k) vb[k] = ldh<FAST>(s2 + tid + k * 256);
      }
#pragma unroll
      for (int k = 0; k < 16; ++k) {
        unsigned* row = (unsigned*)&inA[irow][0];
        row[k * 8 + icol] = va[k];                    // h1 at ushort 0
        if (t > 0) row[128 + k * 8 + icol] = vb[k];   // h2 at ushort HP
      }
    }
    __syncthreads();

    // ---- prefetch x[t+1] into regs: issued now, drained by the end-of-step
    //      barrier -> HBM latency hidden under the MFMA/gates phase.
    if (LAYER == 0 && tid < 128 && t + 1 < T_LEN) {
      int b = tid >> 2, c = tid & 3;
      const float* xp = x + ((size_t)(b0 + b) * T_LEN + (size_t)(t + 1)) * NX + c * 10;
#pragma unroll
      for (int j = 0; j < 10; ++j) xr[j] = xp[j];
    }

    // ---- gate GEMM, operand-swapped: D[r][b] = sum_k WL[r][k] * inA[b][k]
    //      acc0: r-tile Np*2, acc1: r-tile Np*2+1; batch-tile Mt.
    float4v acc0 = {0.f, 0.f, 0.f, 0.f};
    float4v acc1 = {0.f, 0.f, 0.f, 0.f};
#pragma unroll
    for (int ks = 0; ks < KSTEPS; ++ks) {
      short8 a = *(const short8*)&inA[Mt * 16 + l15][ks * 32 + quad * 8];
      acc0 = __builtin_amdgcn_mfma_f32_16x16x32_bf16(wfrag[0][ks], a, acc0, 0, 0, 0);
      acc1 = __builtin_amdgcn_mfma_f32_16x16x32_bf16(wfrag[1][ks], a, acc1, 0, 0, 0);
    }

    // ---- gates in-register: lane holds D[quad*4+reg][l15] = all 4 gates
    //      (i,f,g,o = reg 0..3) of unit lu=rtile*4+quad, batch Mt*16+l15.
    float hA, hB;
    {
      float i0 = sigm(acc0[0] + b4A[0]);
      float f0 = sigm(acc0[1] + b4A[1]);
      float g0 = tanh_f(acc0[2] + b4A[2]);
      float o0 = sigm(acc0[3] + b4A[3]);
      cA = f0 * cA + i0 * g0;
      hA = o0 * tanh_f(cA);
      float i1 = sigm(acc1[0] + b4B[0]);
      float f1 = sigm(acc1[1] + b4B[1]);
      float g1 = tanh_f(acc1[2] + b4B[2]);
      float o1 = sigm(acc1[3] + b4B[3]);
      cB = f1 * cB + i1 * g1;
      hB = o1 * tanh_f(cB);
    }
    // pack unit pairs (adjacent quads = lane^16) and store to the ring:
    // even-quad lanes write dwords at up = Np*4 + (quad>>1) and +2.
    {
      float hA2 = __shfl_xor(hA, 16);
      float hB2 = __shfl_xor(hB, 16);
      if ((quad & 1) == 0) {
        unsigned dwA = (unsigned)f2bf(hA) | ((unsigned)f2bf(hA2) << 16);
        unsigned dwB = (unsigned)f2bf(hB) | ((unsigned)f2bf(hB2) << 16);
        unsigned* dst = (unsigned*)(LAYER ? h2bc : h1bc);
        size_t base = (size_t)(t & (RING - 1)) * RSTEP + (size_t)gb * 4096 +
                      (size_t)gg * 256 + (size_t)(Mt * 16 + l15) * 8;
        sth<FAST>(dst + base + Np * 4 + (quad >> 1), dwA);
        sth<FAST>(dst + base + Np * 4 + 2 + (quad >> 1), dwB);
      }
    }

    // barrier drains every wave's vmcnt(0) -> all h stores (and the x
    // prefetch) are complete; then a relaxed flag store suffices.
    __syncthreads();
    if (tid == 0)
      sth<FAST>((unsigned*)mys, (unsigned)(t + 1));

    // ---- head: y[b, t-1] — distributed: each layer1 wg emits 2 batches
    //      (h2[t-1] for all 32 batches is staged in this wg's inA).
    if (LAYER == 1 && t > 0 && tid < 16) {
      int eb2 = 2 * gg + (tid >> 3), uc = tid & 7;
      float sum = 0.f;
#pragma unroll
      for (int j = 0; j < 4; ++j) {
        short8 hvv = *(const short8*)&inA[eb2][HP + uc * 32 + j * 8];
#pragma unroll
        for (int e = 0; e < 8; ++e)
          sum += bf2f((unsigned short)hvv[e]) * wlinS[uc * 32 + j * 8 + e];
      }
      sum += __shfl_xor(sum, 1);
      sum += __shfl_xor(sum, 2);
      sum += __shfl_xor(sum, 4);
      if ((tid & 7) == 0)
        out[(size_t)(b0 + eb2) * T_LEN + (t - 1)] = sigm(sum + blinv);
    }
  }

  // ---- epilogue: y[:, 511] — distributed: every layer1 wg, 2 batches ----
  if (LAYER == 1) {
    if (wv == 0 && lane < 16) {
      const int* sl = c1s + lane * SLOTS;
      while (__hip_atomic_load(sl, __ATOMIC_RELAXED, __HIP_MEMORY_SCOPE_AGENT) < T_LEN) {
        __builtin_amdgcn_s_sleep(1);
      }
    }
    __syncthreads();
    if (FAST) inv_l1();
    if (tid < 16) {
      int eb2 = 2 * gg + (tid >> 3), uc = tid & 7;
      // units uc*32..+31 of batch b0+eb2 live in gg-blocks 2*uc, 2*uc+1:
      // dword = (2*uc+g)*256 + eb2*8 + j  ->  units (2*uc+g)*16 + 2*j, +1
      const unsigned* base = (const unsigned*)h2bc +
          ((size_t)(511 & (RING - 1)) * RSTEP + (size_t)gb * 4096);
      float sum = 0.f;
#pragma unroll
      for (int g = 0; g < 2; ++g) {
        const unsigned* src = base + (size_t)(2 * uc + g) * 256 + eb2 * 8;
#pragma unroll
        for (int j = 0; j < 8; ++j) {
          unsigned dw = ldh<FAST>(src + j);
          sum += bf2f((unsigned short)(dw & 0xFFFFu)) * wlinS[uc * 32 + g * 16 + 2 * j];
          sum += bf2f((unsigned short)(dw >> 16)) * wlinS[uc * 32 + g * 16 + 2 * j + 1];
        }
      }
      sum += __shfl_xor(sum, 1);
      sum += __shfl_xor(sum, 2);
      sum += __shfl_xor(sum, 4);
      if ((tid & 7) == 0)
        out[(size_t)(b0 + eb2) * T_LEN + 511] = sigm(sum + blinv);
    }
  }
}

// ---------------------------------------------------------------------------
extern "C" __global__ void __launch_bounds__(256, 1) lstm_persist(
    const float* __restrict__ x,
    const float* __restrict__ Wih0, const float* __restrict__ Whh0,
    const float* __restrict__ bih0, const float* __restrict__ bhh0,
    const float* __restrict__ Wih1, const float* __restrict__ Whh1,
    const float* __restrict__ bih1, const float* __restrict__ bhh1,
    const float* __restrict__ Wlin, const float* __restrict__ blin,
    float* __restrict__ out,
    unsigned short* __restrict__ h1bc, unsigned short* __restrict__ h2bc,
    int* __restrict__ cnt) {
  __shared__ unsigned short WL[NR][LDSK];    // 66560 B  bf16 [r][k], r = lu*4+gate
  __shared__ unsigned short inA[MB][LDSK];   // 33280 B  bf16 [b][k]
  __shared__ float gbuf[MB][NR + 4];         //  8704 B  (discovery scratch only)
  __shared__ float biasS[NR];
  __shared__ float wlinS[HP];

  const int tid = threadIdx.x;
  const int wg = blockIdx.x;

  // ---- XCD discovery + dynamic clustering (one-time, off steady state) ----
  const unsigned xcc = ((unsigned)__builtin_amdgcn_s_getreg(GETREG_XCC)) & 15u;
  if (tid == 0) {
    __hip_atomic_store(cnt + XCD_AT(wg), (int)xcc, __ATOMIC_RELAXED,
                       __HIP_MEMORY_SCOPE_AGENT);
    __hip_atomic_fetch_add(cnt + BAR_IDX, 1, __ATOMIC_ACQ_REL,
                           __HIP_MEMORY_SCOPE_AGENT);
    while (__hip_atomic_load(cnt + BAR_IDX, __ATOMIC_ACQUIRE,
                             __HIP_MEMORY_SCOPE_AGENT) < 256)
      __builtin_amdgcn_s_sleep(8);
  }
  __syncthreads();
  int* sx = (int*)&gbuf[0][0];   // reuse gbuf as 256-int scratch
  sx[tid] = __hip_atomic_load(cnt + XCD_AT(tid), __ATOMIC_RELAXED,
                              __HIP_MEMORY_SCOPE_AGENT);
  __syncthreads();
  const int myv = sx[wg];
  int rank = 0;
  unsigned long long hist = 0;   // 8 byte-counters (no scratch array, rule #20)
  bool ok = true;
  for (int j = 0; j < 256; ++j) {
    int v = sx[j];
    if ((unsigned)v > 7u) { ok = false; v = 0; }
    hist += 1ull << (v * 8);
    if (v == myv && j < wg) rank++;
  }
  ok = ok && (hist == 0x2020202020202020ull);   // exactly 32 wgs per XCD
  __syncthreads();   // sx (gbuf) free after this

  // Roles: fast -> cluster = this XCD (gb = xcd id, rank -> layer/unit-group);
  //        slow -> static mapping + sc1 comm ops (always correct).
  int layer, gb, gg;
  if (ok) { gb = myv;       layer = rank >> 4;    gg = rank & 15; }
  else    { layer = wg >> 7; gb = (wg >> 4) & 7;  gg = wg & 15;   }
  const int b0 = gb * MB, u0 = gg * NU;

  // ---- one-time LDS fills ----
  {
    const float* Wih = layer ? Wih1 : Wih0;
    const float* Whh = layer ? Whh1 : Whh0;
    const float* bi = layer ? bih1 : bih0;
    const float* bh = layer ? bhh1 : bhh0;
    const int K = layer ? K1 : K0;
    const int xw = layer ? NH : NX;     // real width of input-part
    const int xofs = layer ? HP : XP;   // where h-part starts
    int r = tid >> 2, c = tid & 3;
    int lu = r >> 2, g = r & 3, ug = u0 + lu;
    int row = g * NH + ug;
    int kq = K >> 2;
    for (int k = c * kq; k < (c + 1) * kq; ++k) {
      float v = 0.f;
      if (ug < NH) {
        if (k < xw) v = Wih[(size_t)row * xw + k];
        else if (k >= xofs && k < xofs + NH) v = Whh[(size_t)row * NH + (k - xofs)];
      }
      WL[r][k] = f2bf(v);
    }
    if (tid < NR) {
      int lu2 = tid >> 2, g2 = tid & 3, ug2 = u0 + lu2;
      biasS[tid] = (ug2 < NH) ? (bi[g2 * NH + ug2] + bh[g2 * NH + ug2]) : 0.f;
    }
    if (tid < HP) wlinS[tid] = (tid < NH) ? Wlin[tid] : 0.f;
    for (int i = tid; i < MB * LDSK; i += 256) ((unsigned short*)inA)[i] = 0;
  }
  __syncthreads();

  float blinv = blin[0];
  int* c0s = cnt + gb * 16 * SLOTS;              // layer0 slots, batch-group gb
  int* c1s = cnt + (8 + gb) * 16 * SLOTS;        // layer1 slots
  int* mys = (layer ? c1s : c0s) + gg * SLOTS;   // own slot

  if (ok) {
    if (layer == 0)
      run_layer<K0 / 32, 0, true>(tid, gg, b0, u0, x, out, blinv, h1bc, h2bc,
                                  c0s, c1s, mys, WL, inA, gbuf, biasS, wlinS);
    else
      run_layer<K1 / 32, 1, true>(tid, gg, b0, u0, x, out, blinv, h1bc, h2bc,
                                  c0s, c1s, mys, WL, inA, gbuf, biasS, wlinS);
  } else {
    if (layer == 0)
      run_layer<K0 / 32, 0, false>(tid, gg, b0, u0, x, out, blinv, h1bc, h2bc,
                                   c0s, c1s, mys, WL, inA, gbuf, biasS, wlinS);
    else
      run_layer<K1 / 32, 1, false>(tid, gg, b0, u0, x, out, blinv, h1bc, h2bc,
                                   c0s, c1s, mys, WL, inA, gbuf, biasS, wlinS);
  }
}

extern "C" __global__ void prep_zero(int* cnt) {
  int i = blockIdx.x * 256 + threadIdx.x;
  if (i < NFLAG)   // flag slots incl. embedded barrier/xcd-id padding ints
    __hip_atomic_store(cnt + i, 0, __ATOMIC_RELAXED, __HIP_MEMORY_SCOPE_AGENT);
}

// ---------------------------------------------------------------------------
extern "C" void kernel_launch(void* const* d_in, const int* in_sizes, int n_in,
                              void* d_out, int out_size, void* d_ws, size_t ws_size,
                              hipStream_t stream) {
  const float* x    = (const float*)d_in[0];
  const float* Wih0 = (const float*)d_in[1];
  const float* Whh0 = (const float*)d_in[2];
  const float* bih0 = (const float*)d_in[3];
  const float* bhh0 = (const float*)d_in[4];
  const float* Wih1 = (const float*)d_in[5];
  const float* Whh1 = (const float*)d_in[6];
  const float* bih1 = (const float*)d_in[7];
  const float* bhh1 = (const float*)d_in[8];
  const float* Wlin = (const float*)d_in[9];
  const float* blin = (const float*)d_in[10];
  float* out = (float*)d_out;

  // workspace carve (same footprint as R3/R7/R8): h rings 2x2MB | counters 16KB
  unsigned short* h1bc = (unsigned short*)d_ws;
  unsigned short* h2bc = h1bc + (size_t)RING * B_TOT * HP;
  int* cnt = (int*)((char*)d_ws + 2u * (size_t)RING * B_TOT * HP * sizeof(unsigned short));

  hipLaunchKernelGGL(prep_zero, dim3(16), dim3(256), 0, stream, cnt);

  void* args[] = {&x, &Wih0, &Whh0, &bih0, &bhh0, &Wih1, &Whh1, &bih1, &bhh1,
                  &Wlin, &blin, &out, &h1bc, &h2bc, &cnt};
  hipLaunchCooperativeKernel((void*)lstm_persist, dim3(256), dim3(256), args, 0u, stream);
}